// Round 8
// baseline (704.482 us; speedup 1.0000x reference)
//
#include <hip/hip_runtime.h>
#include <hip/hip_fp16.h>
#include <cmath>
#include <cstring>

#define HALO 5
#define TSX 32
#define TILE_H 128
#define NCHUNK 4
#define CH 32            // output rows per chunk; 32 rows x 8 quads = 256 thr
#define RING 42          // CH + 2*HALO rows live in LDS ring
#define HSTR 36          // ring row stride in u32 (32 cols + pad, conflict-free)
#define PLANE (RING * HSTR)   // u32 per field-pair plane
#define WIDTH 512
#define HEIGHT 512

// f32 weights for phase A + host-packed half2 weights for phase B; both
// consumed from SGPRs (a VGPR-resident weight table tipped the allocator
// into spilling in round 6).
struct GW { float g[11]; uint32_t wpk[11]; };

typedef float f32x2 __attribute__((ext_vector_type(2)));

__device__ __forceinline__ uint32_t pk2(float a, float b)
{
    auto h = __builtin_amdgcn_cvt_pkrtz(a, b);   // single v_cvt_pkrtz_f16_f32
    return __builtin_bit_cast(uint32_t, h);
}

__device__ __forceinline__ float ssim2(float mu1, float mu2,
                                       float x2b, float y2b, float xyb)
{
    const float C1 = 1e-4f, C2 = 9e-4f;
    float mu12 = mu1 * mu2;
    float num  = (2.f * mu12 + C1) * (2.f * (xyb - mu12) + C2);
    float den  = (mu1 * mu1 + mu2 * mu2 + C1) *
                 ((x2b - mu1 * mu1) + (y2b - mu2 * mu2) + C2);
    return num * __builtin_amdgcn_rcpf(den);   // ~1 ulp; threshold is 2e-2
}

// H-blur one image row into ring slot `slot` as 4 fp16x2 planes.
// Packed-f32 core: accumulators are float2 field-pairs matching the plane
// layout (F,A),(B,F2),(A2,B2),(FA,FB) -> v_pk_fma_f32 halves the FMA count
// (352 scalar -> 176 packed per row-lane).
template<bool CX, bool CY>
__device__ __forceinline__ void hblur_row(
    const float* __restrict__ rowf, const float* __restrict__ rowa,
    const float* __restrict__ rowb, bool yok, int gx0, int slot, int qA,
    uint32_t (* __restrict__ hb)[PLANE], const GW& gw)
{
    f32x2 acc[4][4];                 // [out-col jj][plane p]
    #pragma unroll
    for (int jj = 0; jj < 4; ++jj)
        #pragma unroll
        for (int p = 0; p < 4; ++p) acc[jj][p] = f32x2{0.f, 0.f};

    #pragma unroll
    for (int k = 0; k < 5; ++k) {
        const int g = gx0 + 4 * k;
        float4 vf, va, vb;
        if (CX || CY) {
            bool ok = true;
            if (CY) ok = yok;
            if (CX) ok = ok && ((unsigned)g <= (unsigned)(WIDTH - 4));
            vf = ok ? *(const float4*)(rowf + g) : make_float4(0,0,0,0);
            va = ok ? *(const float4*)(rowa + g) : make_float4(0,0,0,0);
            vb = ok ? *(const float4*)(rowb + g) : make_float4(0,0,0,0);
        } else {
            vf = *(const float4*)(rowf + g);
            va = *(const float4*)(rowa + g);
            vb = *(const float4*)(rowb + g);
        }
        const float fs[4] = { vf.x, vf.y, vf.z, vf.w };
        const float as[4] = { va.x, va.y, va.z, va.w };
        const float bs[4] = { vb.x, vb.y, vb.z, vb.w };
        #pragma unroll
        for (int cc = 0; cc < 4; ++cc) {
            const int tt = 4 * k + cc - 3;    // window col 0..13
            if (tt < 0 || tt > 13) continue;  // static prune
            const float f = fs[cc], a = as[cc], b = bs[cc];
            f32x2 P[4];
            P[0] = f32x2{f, a};
            P[1] = f32x2{b, f * f};
            P[2] = f32x2{a * a, b * b};
            P[3] = f32x2{f * a, f * b};
            #pragma unroll
            for (int jj = 0; jj < 4; ++jj) {
                const int u = tt - jj;        // tap index
                if (u >= 0 && u <= 10) {
                    const float w = gw.g[u];
                    const f32x2 w2 = {w, w};
                    #pragma unroll
                    for (int p = 0; p < 4; ++p)
                        acc[jj][p] = __builtin_elementwise_fma(w2, P[p],
                                                               acc[jj][p]);
                }
            }
        }
    }
    // plane p <- pair (acc.x, acc.y), cols 4qA..4qA+3, one b128/plane
    #pragma unroll
    for (int p = 0; p < 4; ++p) {
        uint4 v = make_uint4(pk2(acc[0][p].x, acc[0][p].y),
                             pk2(acc[1][p].x, acc[1][p].y),
                             pk2(acc[2][p].x, acc[2][p].y),
                             pk2(acc[3][p].x, acc[3][p].y));
        *(uint4*)(&hb[p][slot * HSTR + 4 * qA]) = v;
    }
}

// Phase-alternating, ALL 256 threads active in BOTH phases (the 4:1 A:B work
// ratio makes wave-specialization structurally <=62% utilized — measured
// rounds 3/6; alternation has no such cap).
template<bool CX, bool CY>
__device__ __forceinline__ float tile_compute(
    const float* __restrict__ fI, const float* __restrict__ aI,
    const float* __restrict__ bI, uint32_t (* __restrict__ hb)[PLANE],
    const GW& gw, int tid, int x0, int y0, size_t pbase)
{
    const int rA  = tid >> 3;            // phase A row 0..31
    const int qA  = tid & 7;
    const int gx0 = x0 + 4 * qA - 8;     // first loaded global col (5 quads)
    const int jB  = tid & 31;            // phase B col
    const int rgB = tid >> 5;            // phase B row-group 0..7 (4 rows each)

    float part = 0.f;

    // ---- prologue: prime ring rows 0..41 (two STATIC calls, no dyn loop) ----
    {
        const int yy = y0 - HALO + rA;
        const bool yok = CY ? ((unsigned)yy < (unsigned)HEIGHT) : true;
        hblur_row<CX, CY>(fI + pbase + (size_t)yy * WIDTH,
                          aI + pbase + (size_t)yy * WIDTH,
                          bI + pbase + (size_t)yy * WIDTH,
                          yok, gx0, rA, qA, hb, gw);
    }
    if (rA < 10) {
        const int t  = 32 + rA;
        const int yy = y0 - HALO + t;
        const bool yok = CY ? ((unsigned)yy < (unsigned)HEIGHT) : true;
        hblur_row<CX, CY>(fI + pbase + (size_t)yy * WIDTH,
                          aI + pbase + (size_t)yy * WIDTH,
                          bI + pbase + (size_t)yy * WIDTH,
                          yok, gx0, t, qA, hb, gw);
    }
    __syncthreads();

    #pragma unroll 1
    for (int c = 0; c < NCHUNK; ++c) {
        if (c) {
            // ---- phase A: 32 new rows [32c+10, 32c+42) for chunk c ----
            const int t = CH * c + 10 + rA;        // 42..137
            int slot = t;
            slot -= (slot >= RING) ? RING : 0;
            slot -= (slot >= RING) ? RING : 0;
            slot -= (slot >= RING) ? RING : 0;
            const int yy = y0 - HALO + t;
            const bool yok = CY ? ((unsigned)yy < (unsigned)HEIGHT) : true;
            hblur_row<CX, CY>(fI + pbase + (size_t)yy * WIDTH,
                              aI + pbase + (size_t)yy * WIDTH,
                              bI + pbase + (size_t)yy * WIDTH,
                              yok, gx0, slot, qA, hb, gw);
            __syncthreads();
        }

        // ---- phase B: packed-fp16 vertical blur + SSIM, 32 rows ----
        int sb = CH * c + 4 * rgB;        // <=124
        sb -= (sb >= RING) ? RING : 0;
        sb -= (sb >= RING) ? RING : 0;
        __half2 acc2[4][4];               // [ri][plane], static-indexed only
        #pragma unroll
        for (int ri = 0; ri < 4; ++ri)
            #pragma unroll
            for (int p = 0; p < 4; ++p)
                acc2[ri][p] = __float2half2_rn(0.f);
        #pragma unroll
        for (int k = 0; k < 14; ++k) {
            int t = sb + k;
            t -= (t >= RING) ? RING : 0;
            const uint32_t* hp = &hb[0][t * HSTR + jB];
            __half2 hv[4];
            #pragma unroll
            for (int p = 0; p < 4; ++p)
                hv[p] = __builtin_bit_cast(__half2, hp[p * PLANE]);
            #pragma unroll
            for (int ri = 0; ri < 4; ++ri) {
                const int u = k - ri;
                if (u >= 0 && u <= 10) {
                    // u is compile-time -> gw.wpk[u] stays in SGPRs
                    const __half2 w = __builtin_bit_cast(__half2, gw.wpk[u]);
                    #pragma unroll
                    for (int p = 0; p < 4; ++p)
                        acc2[ri][p] = __hfma2(w, hv[p], acc2[ri][p]);
                }
            }
        }
        #pragma unroll
        for (int ri = 0; ri < 4; ++ri) {
            // planes: 0=(F,A) 1=(B,F2) 2=(A2,B2) 3=(FA,FB)
            const float F  = __low2float (acc2[ri][0]);
            const float A  = __high2float(acc2[ri][0]);
            const float B  = __low2float (acc2[ri][1]);
            const float F2 = __high2float(acc2[ri][1]);
            const float A2 = __low2float (acc2[ri][2]);
            const float B2 = __high2float(acc2[ri][2]);
            const float FA = __low2float (acc2[ri][3]);
            const float FB = __high2float(acc2[ri][3]);
            part += ssim2(F, A, F2, A2, FA);
            part += ssim2(F, B, F2, B2, FB);
        }
        __syncthreads();
    }
    return part;
}

// (256,6): VGPR cap 85; body compiles to ~64 spill-free (round 7), so the
// cap is slack. Round-5's spill at (256,6) came from the VGPR-resident
// weight table, since removed. Occupancy experiment: (256,3) measured 35%,
// (256,6) expected 55-70% at identical LDS (round-5 evidence).
// Spill tripwire: WRITE_SIZE must stay ~120 KB.
__global__ __launch_bounds__(256, 6)
void ssim_tile(const float* __restrict__ fI, const float* __restrict__ aI,
               const float* __restrict__ bI, float* __restrict__ bsum,
               GW gw)
{
    __shared__ __align__(16) uint32_t hb[4][PLANE];   // 24.2 KB
    __shared__ float red[4];

    const int tid = threadIdx.x;
    const int x0 = blockIdx.x * TSX;
    const int y0 = blockIdx.y * TILE_H;
    const size_t pbase = (size_t)blockIdx.z * (size_t)(WIDTH * HEIGHT);

    const bool ex = (blockIdx.x == 0) || (blockIdx.x == gridDim.x - 1);
    const bool ey = (blockIdx.y == 0) || (blockIdx.y == gridDim.y - 1);

    float part;
    if (!ex && !ey)
        part = tile_compute<false, false>(fI, aI, bI, hb, gw, tid, x0, y0, pbase);
    else if (!ex)
        part = tile_compute<false, true >(fI, aI, bI, hb, gw, tid, x0, y0, pbase);
    else if (!ey)
        part = tile_compute<true,  false>(fI, aI, bI, hb, gw, tid, x0, y0, pbase);
    else
        part = tile_compute<true,  true >(fI, aI, bI, hb, gw, tid, x0, y0, pbase);

    // ---- reduction -> per-block partial (no atomics) ----
    #pragma unroll
    for (int off = 32; off > 0; off >>= 1) part += __shfl_down(part, off);
    if ((tid & 63) == 0) red[tid >> 6] = part;
    __syncthreads();
    if (tid == 0) {
        int bid = blockIdx.x + gridDim.x * (blockIdx.y + gridDim.y * blockIdx.z);
        bsum[bid] = red[0] + red[1] + red[2] + red[3];
    }
}

__global__ __launch_bounds__(256)
void ssim_final(const float* __restrict__ bsum, float* __restrict__ out,
                int nb, float invTwoN)
{
    __shared__ float sred[4];
    float s = 0.f;
    for (int i = threadIdx.x; i < nb; i += 256) s += bsum[i];
    #pragma unroll
    for (int off = 32; off > 0; off >>= 1) s += __shfl_down(s, off);
    if ((threadIdx.x & 63) == 0) sred[threadIdx.x >> 6] = s;
    __syncthreads();
    if (threadIdx.x == 0)
        out[0] = 1.f - (sred[0] + sred[1] + sred[2] + sred[3]) * invTwoN;
}

// host-side float->half (RNE); weights are small positive normals
static uint16_t f2h(float f)
{
    uint32_t x; std::memcpy(&x, &f, 4);
    uint32_t s = (x >> 16) & 0x8000u;
    int      e = (int)((x >> 23) & 0xff) - 127 + 15;
    uint32_t m = x & 0x007fffffu;
    uint32_t base = ((uint32_t)e << 10) | (m >> 13);
    uint32_t rem  = m & 0x1fffu;
    if (rem > 0x1000u || (rem == 0x1000u && (base & 1u))) base++;
    return (uint16_t)(s | base);
}

extern "C" void kernel_launch(void* const* d_in, const int* in_sizes, int n_in,
                              void* d_out, int out_size, void* d_ws, size_t ws_size,
                              hipStream_t stream)
{
    const float* f  = (const float*)d_in[0];
    const float* s1 = (const float*)d_in[1];
    const float* s2 = (const float*)d_in[2];
    float* out  = (float*)d_out;
    float* bsum = (float*)d_ws;          // 3072 floats = 12 KB scratch

    const int N = in_sizes[0];           // 48 * 512 * 512
    const int planes = N / (WIDTH * HEIGHT);

    GW gw;
    double gd[11], gs = 0.0;
    for (int i = 0; i < 11; ++i) {
        double d = (double)(i - 5);
        gd[i] = exp(-(d * d) / 4.5);     // 2*sigma^2 = 4.5
        gs += gd[i];
    }
    for (int i = 0; i < 11; ++i) {
        gw.g[i] = (float)(gd[i] / gs);
        uint32_t h = f2h(gw.g[i]);
        gw.wpk[i] = (h << 16) | h;       // broadcast half2
    }

    dim3 grid(WIDTH / TSX, HEIGHT / TILE_H, planes);
    const int nb = (WIDTH / TSX) * (HEIGHT / TILE_H) * planes;
    ssim_tile<<<grid, dim3(256), 0, stream>>>(f, s1, s2, bsum, gw);
    ssim_final<<<1, dim3(256), 0, stream>>>(bsum, out, nb, 0.5f / (float)N);
}

// Round 9
// 229.161 us; speedup vs baseline: 3.0742x; 3.0742x over previous
//
#include <hip/hip_runtime.h>
#include <hip/hip_fp16.h>
#include <cmath>
#include <cstring>

#define HALO 5
#define TSX 32
#define TILE_H 128
#define NCHUNK 4
#define CH 32            // output rows per chunk; 32 rows x 8 quads = 256 thr
#define RING 42          // CH + 2*HALO rows live in LDS ring
#define HSTR 36          // ring row stride in u32 (32 cols + pad, conflict-free)
#define PLANE (RING * HSTR)   // u32 per field-pair plane
#define WIDTH 512
#define HEIGHT 512

// f32 weights for phase A + host-packed half2 weights for phase B; both
// consumed from SGPRs (a VGPR-resident weight table tipped the allocator
// into spilling in round 6).
struct GW { float g[11]; uint32_t wpk[11]; };

typedef float f32x2 __attribute__((ext_vector_type(2)));

__device__ __forceinline__ uint32_t pk2(float a, float b)
{
    auto h = __builtin_amdgcn_cvt_pkrtz(a, b);   // single v_cvt_pkrtz_f16_f32
    return __builtin_bit_cast(uint32_t, h);
}

__device__ __forceinline__ float ssim2(float mu1, float mu2,
                                       float x2b, float y2b, float xyb)
{
    const float C1 = 1e-4f, C2 = 9e-4f;
    float mu12 = mu1 * mu2;
    float num  = (2.f * mu12 + C1) * (2.f * (xyb - mu12) + C2);
    float den  = (mu1 * mu1 + mu2 * mu2 + C1) *
                 ((x2b - mu1 * mu1) + (y2b - mu2 * mu2) + C2);
    return num * __builtin_amdgcn_rcpf(den);   // ~1 ulp; threshold is 2e-2
}

// H-blur one image row into ring slot `slot` as 4 fp16x2 planes.
// Packed-f32 core: accumulators are float2 field-pairs matching the plane
// layout (F,A),(B,F2),(A2,B2),(FA,FB) -> v_pk_fma_f32 halves the FMA count
// (352 scalar -> 176 packed per row-lane). Register pressure unchanged
// (32 VGPRs of accumulator either way).
template<bool CX, bool CY>
__device__ __forceinline__ void hblur_row(
    const float* __restrict__ rowf, const float* __restrict__ rowa,
    const float* __restrict__ rowb, bool yok, int gx0, int slot, int qA,
    uint32_t (* __restrict__ hb)[PLANE], const GW& gw)
{
    f32x2 acc[4][4];                 // [out-col jj][plane p]
    #pragma unroll
    for (int jj = 0; jj < 4; ++jj)
        #pragma unroll
        for (int p = 0; p < 4; ++p) acc[jj][p] = f32x2{0.f, 0.f};

    #pragma unroll
    for (int k = 0; k < 5; ++k) {
        const int g = gx0 + 4 * k;
        float4 vf, va, vb;
        if (CX || CY) {
            bool ok = true;
            if (CY) ok = yok;
            if (CX) ok = ok && ((unsigned)g <= (unsigned)(WIDTH - 4));
            vf = ok ? *(const float4*)(rowf + g) : make_float4(0,0,0,0);
            va = ok ? *(const float4*)(rowa + g) : make_float4(0,0,0,0);
            vb = ok ? *(const float4*)(rowb + g) : make_float4(0,0,0,0);
        } else {
            vf = *(const float4*)(rowf + g);
            va = *(const float4*)(rowa + g);
            vb = *(const float4*)(rowb + g);
        }
        const float fs[4] = { vf.x, vf.y, vf.z, vf.w };
        const float as[4] = { va.x, va.y, va.z, va.w };
        const float bs[4] = { vb.x, vb.y, vb.z, vb.w };
        #pragma unroll
        for (int cc = 0; cc < 4; ++cc) {
            const int tt = 4 * k + cc - 3;    // window col 0..13
            if (tt < 0 || tt > 13) continue;  // static prune
            const float f = fs[cc], a = as[cc], b = bs[cc];
            f32x2 P[4];
            P[0] = f32x2{f, a};
            P[1] = f32x2{b, f * f};
            P[2] = f32x2{a * a, b * b};
            P[3] = f32x2{f * a, f * b};
            #pragma unroll
            for (int jj = 0; jj < 4; ++jj) {
                const int u = tt - jj;        // tap index
                if (u >= 0 && u <= 10) {
                    const float w = gw.g[u];
                    const f32x2 w2 = {w, w};
                    #pragma unroll
                    for (int p = 0; p < 4; ++p)
                        acc[jj][p] = __builtin_elementwise_fma(w2, P[p],
                                                               acc[jj][p]);
                }
            }
        }
    }
    // plane p <- pair (acc.x, acc.y), cols 4qA..4qA+3, one b128/plane
    #pragma unroll
    for (int p = 0; p < 4; ++p) {
        uint4 v = make_uint4(pk2(acc[0][p].x, acc[0][p].y),
                             pk2(acc[1][p].x, acc[1][p].y),
                             pk2(acc[2][p].x, acc[2][p].y),
                             pk2(acc[3][p].x, acc[3][p].y));
        *(uint4*)(&hb[p][slot * HSTR + 4 * qA]) = v;
    }
}

// Phase-alternating, ALL 256 threads active in BOTH phases.
template<bool CX, bool CY>
__device__ __forceinline__ float tile_compute(
    const float* __restrict__ fI, const float* __restrict__ aI,
    const float* __restrict__ bI, uint32_t (* __restrict__ hb)[PLANE],
    const GW& gw, int tid, int x0, int y0, size_t pbase)
{
    const int rA  = tid >> 3;            // phase A row 0..31
    const int qA  = tid & 7;
    const int gx0 = x0 + 4 * qA - 8;     // first loaded global col (5 quads)
    const int jB  = tid & 31;            // phase B col
    const int rgB = tid >> 5;            // phase B row-group 0..7 (4 rows each)

    float part = 0.f;

    // ---- prologue: prime ring rows 0..41 (two STATIC calls, no dyn loop) ----
    {
        const int yy = y0 - HALO + rA;
        const bool yok = CY ? ((unsigned)yy < (unsigned)HEIGHT) : true;
        hblur_row<CX, CY>(fI + pbase + (size_t)yy * WIDTH,
                          aI + pbase + (size_t)yy * WIDTH,
                          bI + pbase + (size_t)yy * WIDTH,
                          yok, gx0, rA, qA, hb, gw);
    }
    if (rA < 10) {
        const int t  = 32 + rA;
        const int yy = y0 - HALO + t;
        const bool yok = CY ? ((unsigned)yy < (unsigned)HEIGHT) : true;
        hblur_row<CX, CY>(fI + pbase + (size_t)yy * WIDTH,
                          aI + pbase + (size_t)yy * WIDTH,
                          bI + pbase + (size_t)yy * WIDTH,
                          yok, gx0, t, qA, hb, gw);
    }
    __syncthreads();

    #pragma unroll 1
    for (int c = 0; c < NCHUNK; ++c) {
        if (c) {
            // ---- phase A: 32 new rows [32c+10, 32c+42) for chunk c ----
            const int t = CH * c + 10 + rA;        // 42..137
            int slot = t;
            slot -= (slot >= RING) ? RING : 0;
            slot -= (slot >= RING) ? RING : 0;
            slot -= (slot >= RING) ? RING : 0;
            const int yy = y0 - HALO + t;
            const bool yok = CY ? ((unsigned)yy < (unsigned)HEIGHT) : true;
            hblur_row<CX, CY>(fI + pbase + (size_t)yy * WIDTH,
                              aI + pbase + (size_t)yy * WIDTH,
                              bI + pbase + (size_t)yy * WIDTH,
                              yok, gx0, slot, qA, hb, gw);
            __syncthreads();
        }

        // ---- phase B: packed-fp16 vertical blur + SSIM, 32 rows ----
        int sb = CH * c + 4 * rgB;        // <=124
        sb -= (sb >= RING) ? RING : 0;
        sb -= (sb >= RING) ? RING : 0;
        __half2 acc2[4][4];               // [ri][plane], static-indexed only
        #pragma unroll
        for (int ri = 0; ri < 4; ++ri)
            #pragma unroll
            for (int p = 0; p < 4; ++p)
                acc2[ri][p] = __float2half2_rn(0.f);
        #pragma unroll
        for (int k = 0; k < 14; ++k) {
            int t = sb + k;
            t -= (t >= RING) ? RING : 0;
            const uint32_t* hp = &hb[0][t * HSTR + jB];
            __half2 hv[4];
            #pragma unroll
            for (int p = 0; p < 4; ++p)
                hv[p] = __builtin_bit_cast(__half2, hp[p * PLANE]);
            #pragma unroll
            for (int ri = 0; ri < 4; ++ri) {
                const int u = k - ri;
                if (u >= 0 && u <= 10) {
                    // u is compile-time -> gw.wpk[u] stays in SGPRs
                    const __half2 w = __builtin_bit_cast(__half2, gw.wpk[u]);
                    #pragma unroll
                    for (int p = 0; p < 4; ++p)
                        acc2[ri][p] = __hfma2(w, hv[p], acc2[ri][p]);
                }
            }
        }
        #pragma unroll
        for (int ri = 0; ri < 4; ++ri) {
            // planes: 0=(F,A) 1=(B,F2) 2=(A2,B2) 3=(FA,FB)
            const float F  = __low2float (acc2[ri][0]);
            const float A  = __high2float(acc2[ri][0]);
            const float B  = __low2float (acc2[ri][1]);
            const float F2 = __high2float(acc2[ri][1]);
            const float A2 = __low2float (acc2[ri][2]);
            const float B2 = __high2float(acc2[ri][2]);
            const float FA = __low2float (acc2[ri][3]);
            const float FB = __high2float(acc2[ri][3]);
            part += ssim2(F, A, F2, A2, FA);
            part += ssim2(F, B, F2, B2, FB);
        }
        __syncthreads();
    }
    return part;
}

// (256,3): ONLY safe bound for this body family. Measured: (256,6) -> VGPR 40
// + ~1 GB spill traffic (rounds 5, 8); (256,4) -> VGPR 64 + 36 MB spill
// (round 6); (256,3) -> spill-free (rounds 3, 7). The waves-per-EU attr
// steers the allocator's occupancy heuristic, not just the cap — it chases
// the implied occupancy by spilling. DO NOT raise.
__global__ __launch_bounds__(256, 3)
void ssim_tile(const float* __restrict__ fI, const float* __restrict__ aI,
               const float* __restrict__ bI, float* __restrict__ bsum,
               GW gw)
{
    __shared__ __align__(16) uint32_t hb[4][PLANE];   // 24.2 KB
    __shared__ float red[4];

    const int tid = threadIdx.x;
    const int x0 = blockIdx.x * TSX;
    const int y0 = blockIdx.y * TILE_H;
    const size_t pbase = (size_t)blockIdx.z * (size_t)(WIDTH * HEIGHT);

    const bool ex = (blockIdx.x == 0) || (blockIdx.x == gridDim.x - 1);
    const bool ey = (blockIdx.y == 0) || (blockIdx.y == gridDim.y - 1);

    float part;
    if (!ex && !ey)
        part = tile_compute<false, false>(fI, aI, bI, hb, gw, tid, x0, y0, pbase);
    else if (!ex)
        part = tile_compute<false, true >(fI, aI, bI, hb, gw, tid, x0, y0, pbase);
    else if (!ey)
        part = tile_compute<true,  false>(fI, aI, bI, hb, gw, tid, x0, y0, pbase);
    else
        part = tile_compute<true,  true >(fI, aI, bI, hb, gw, tid, x0, y0, pbase);

    // ---- reduction -> per-block partial (no atomics) ----
    #pragma unroll
    for (int off = 32; off > 0; off >>= 1) part += __shfl_down(part, off);
    if ((tid & 63) == 0) red[tid >> 6] = part;
    __syncthreads();
    if (tid == 0) {
        int bid = blockIdx.x + gridDim.x * (blockIdx.y + gridDim.y * blockIdx.z);
        bsum[bid] = red[0] + red[1] + red[2] + red[3];
    }
}

__global__ __launch_bounds__(256)
void ssim_final(const float* __restrict__ bsum, float* __restrict__ out,
                int nb, float invTwoN)
{
    __shared__ float sred[4];
    float s = 0.f;
    for (int i = threadIdx.x; i < nb; i += 256) s += bsum[i];
    #pragma unroll
    for (int off = 32; off > 0; off >>= 1) s += __shfl_down(s, off);
    if ((threadIdx.x & 63) == 0) sred[threadIdx.x >> 6] = s;
    __syncthreads();
    if (threadIdx.x == 0)
        out[0] = 1.f - (sred[0] + sred[1] + sred[2] + sred[3]) * invTwoN;
}

// host-side float->half (RNE); weights are small positive normals
static uint16_t f2h(float f)
{
    uint32_t x; std::memcpy(&x, &f, 4);
    uint32_t s = (x >> 16) & 0x8000u;
    int      e = (int)((x >> 23) & 0xff) - 127 + 15;
    uint32_t m = x & 0x007fffffu;
    uint32_t base = ((uint32_t)e << 10) | (m >> 13);
    uint32_t rem  = m & 0x1fffu;
    if (rem > 0x1000u || (rem == 0x1000u && (base & 1u))) base++;
    return (uint16_t)(s | base);
}

extern "C" void kernel_launch(void* const* d_in, const int* in_sizes, int n_in,
                              void* d_out, int out_size, void* d_ws, size_t ws_size,
                              hipStream_t stream)
{
    const float* f  = (const float*)d_in[0];
    const float* s1 = (const float*)d_in[1];
    const float* s2 = (const float*)d_in[2];
    float* out  = (float*)d_out;
    float* bsum = (float*)d_ws;          // 3072 floats = 12 KB scratch

    const int N = in_sizes[0];           // 48 * 512 * 512
    const int planes = N / (WIDTH * HEIGHT);

    GW gw;
    double gd[11], gs = 0.0;
    for (int i = 0; i < 11; ++i) {
        double d = (double)(i - 5);
        gd[i] = exp(-(d * d) / 4.5);     // 2*sigma^2 = 4.5
        gs += gd[i];
    }
    for (int i = 0; i < 11; ++i) {
        gw.g[i] = (float)(gd[i] / gs);
        uint32_t h = f2h(gw.g[i]);
        gw.wpk[i] = (h << 16) | h;       // broadcast half2
    }

    dim3 grid(WIDTH / TSX, HEIGHT / TILE_H, planes);
    const int nb = (WIDTH / TSX) * (HEIGHT / TILE_H) * planes;
    ssim_tile<<<grid, dim3(256), 0, stream>>>(f, s1, s2, bsum, gw);
    ssim_final<<<1, dim3(256), 0, stream>>>(bsum, out, nb, 0.5f / (float)N);
}